// Round 2
// baseline (151.659 us; speedup 1.0000x reference)
//
#include <hip/hip_runtime.h>

// VQ-VAE quantization forward for MI355X (gfx950).
// outputs (concat in d_out, fp32): quantized_ [16*4096*256], commitment_loss [1], perplexity [1]
//
// v3: barrier-free main loop, L2-direct B, no epilogue x re-read.
//   - 512 blocks x 256 threads (4 waves). Wave owns 32 rows (two 16-row MFMA A-sets).
//   - Each wave scans all 512 codes in 32 tiles of 16, B-fragments loaded straight from
//     L2 (bswz 256 KB, XCD-L2-hot) into registers, double-buffered. No LDS staging, no
//     barriers in the main loop -> waves drift apart and phases overlap naturally.
//   - Output value is algebraically exactly q (x + sg(q-x) -> q; (q+q)/2 = q), so the
//     epilogue never re-reads x. Commitment loss via ||x||^2 + cA[c] + cB[c]*score with
//     cA = q2*(1-1/s), cB = -2s precomputed in prep (s = ||emb||+1e-4, q2 = ||emb||^2).
//   - Score path (K=32 steps, single f32 acc chain, init -bias) is bit-identical to v2.

typedef _Float16 half8_t __attribute__((ext_vector_type(8)));
typedef _Float16 half4_t __attribute__((ext_vector_type(4)));
typedef float f32x4 __attribute__((ext_vector_type(4)));

static constexpr int kRows = 65536;   // N*T
static constexpr int kD = 256;
static constexpr int kM = 512;
static constexpr int kBM = 128;       // rows per block (4 waves x 32)

// ---------------- prep: normalize codebook -> fp16 in MFMA B-fragment order, bias, cA/cB, zero hist/loss
// swz layout (halves): [group g=c>>4][ko=k>>5][lane = qd*16 + (c&15)][j = k&7], qd=(k>>3)&3.
// A wave's contiguous 1 KB read at (g*4096 + ko*512 + lane*8) halves yields exactly the
// mfma_f32_16x16x32_f16 B-fragment: lane holds B[k=ko*32+(lane>>4)*8+j][n=lane&15].
__global__ void vq_prep(const float* __restrict__ emb, _Float16* __restrict__ swz,
                        float* __restrict__ bias, float2* __restrict__ cab,
                        unsigned int* __restrict__ hist, float* __restrict__ loss) {
    const int j = blockIdx.x;       // code row, 512 blocks
    const int lane = threadIdx.x;   // 64 threads = 1 wave
    float4 v = ((const float4*)(emb + j * kD))[lane];
    float ss = v.x * v.x + v.y * v.y + v.z * v.z + v.w * v.w;
    #pragma unroll
    for (int off = 32; off > 0; off >>= 1) ss += __shfl_xor(ss, off);
    const float s = sqrtf(ss) + 1e-4f;      // ||emb_raw|| + 1e-4
    const float scale = 1.0f / s;
    if (lane == 0) {
        bias[j] = 0.5f * ss * scale * scale;            // 0.5*||e_norm||^2
        cab[j] = make_float2(ss * (1.0f - scale),       // cA = q2 - 2*s*bias = q2*(1-1/s)
                             -2.0f * s);                // cB
    }
    half4_t h;
    h[0] = (_Float16)(v.x * scale);
    h[1] = (_Float16)(v.y * scale);
    h[2] = (_Float16)(v.z * scale);
    h[3] = (_Float16)(v.w * scale);
    const int k0 = lane * 4;        // this lane covers k0..k0+3 (within one 8-half j-chunk)
    const int ko = k0 >> 5;
    const int qd = (k0 >> 3) & 3;
    const int jj = k0 & 7;          // 0 or 4
    const int off_h = (j >> 4) * 4096 + ko * 512 + (qd * 16 + (j & 15)) * 8 + jj;
    *(half4_t*)(swz + off_h) = h;
    if (j == 0) {
        for (int b = lane; b < kM; b += 64) hist[b] = 0u;
        if (lane == 0) loss[0] = 0.0f;
    }
}

// ---------------- main: 32 rows/wave, L2-direct B, barrier-free argmax + gather + loss ----------------
__global__ __launch_bounds__(256, 2) void vq_main(
    const float* __restrict__ x, const float* __restrict__ emb,
    const _Float16* __restrict__ bswz, const float* __restrict__ bias,
    const float2* __restrict__ cab,
    unsigned int* __restrict__ hist, float* __restrict__ loss_accum,
    float* __restrict__ out) {
    __shared__ unsigned int lhist[kM];      // 2048 B
    __shared__ int lidx[kBM];               // 512 B
    __shared__ float lred[16];              // 64 B

    const int t = threadIdx.x;              // 0..255, 4 waves
    const int wave = t >> 6;
    const int lane = t & 63;
    const int ln = lane & 15;
    const int qd = lane >> 4;
    const int r0 = blockIdx.x * kBM + wave * 32;   // wave's 32 rows

    lhist[t] = 0u;
    lhist[t + 256] = 0u;
    __syncthreads();                        // hist init visible before any leader atomic

    // B tile 0 prologue (L2) + its bias
    half8_t ba[8], bb[8];
    {
        const _Float16* b0 = bswz + lane * 8;
        #pragma unroll
        for (int ko = 0; ko < 8; ++ko) ba[ko] = *(const half8_t*)(b0 + ko * 512);
    }
    float bias_c = bias[ln];

    // A fragments (two 16-row sets), loaded once; ||x||^2 per row accumulated in fp32.
    // Lane reads 32 contiguous bytes per (row-set, ko): dims qd*8+ko*32 .. +8.
    half8_t a0[8], a1[8];
    float ssq0 = 0.0f, ssq1 = 0.0f;
    {
        const float* xr0 = x + (size_t)(r0 + ln) * kD + qd * 8;
        const float* xr1 = xr0 + 16 * kD;
        #pragma unroll
        for (int ko = 0; ko < 8; ++ko) {
            const float4 u0 = *(const float4*)(xr0 + ko * 32);
            const float4 u1 = *(const float4*)(xr0 + ko * 32 + 4);
            const float4 w0 = *(const float4*)(xr1 + ko * 32);
            const float4 w1 = *(const float4*)(xr1 + ko * 32 + 4);
            half8_t h0, h1;
            h0[0] = (_Float16)u0.x; h0[1] = (_Float16)u0.y;
            h0[2] = (_Float16)u0.z; h0[3] = (_Float16)u0.w;
            h0[4] = (_Float16)u1.x; h0[5] = (_Float16)u1.y;
            h0[6] = (_Float16)u1.z; h0[7] = (_Float16)u1.w;
            h1[0] = (_Float16)w0.x; h1[1] = (_Float16)w0.y;
            h1[2] = (_Float16)w0.z; h1[3] = (_Float16)w0.w;
            h1[4] = (_Float16)w1.x; h1[5] = (_Float16)w1.y;
            h1[6] = (_Float16)w1.z; h1[7] = (_Float16)w1.w;
            a0[ko] = h0; a1[ko] = h1;
            ssq0 += u0.x*u0.x + u0.y*u0.y + u0.z*u0.z + u0.w*u0.w
                  + u1.x*u1.x + u1.y*u1.y + u1.z*u1.z + u1.w*u1.w;
            ssq1 += w0.x*w0.x + w0.y*w0.y + w0.z*w0.z + w0.w*w0.w
                  + w1.x*w1.x + w1.y*w1.y + w1.z*w1.z + w1.w*w1.w;
        }
    }
    // full row ssq = sum over the 4 qd-lanes sharing ln
    ssq0 += __shfl_xor(ssq0, 16); ssq0 += __shfl_xor(ssq0, 32);
    ssq1 += __shfl_xor(ssq1, 16); ssq1 += __shfl_xor(ssq1, 32);

    float bv0[4] = {-1e30f, -1e30f, -1e30f, -1e30f};
    float bv1[4] = {-1e30f, -1e30f, -1e30f, -1e30f};
    int bi0[4] = {0, 0, 0, 0};
    int bi1[4] = {0, 0, 0, 0};

    // score = x.e_norm - 0.5*||e_norm||^2; single f32 acc chain per row-set (bit-matches v2)
    auto compute = [&](int g, const half8_t (&b)[8], float bg) {
        f32x4 acc0 = {-bg, -bg, -bg, -bg};
        f32x4 acc1 = {-bg, -bg, -bg, -bg};
        #pragma unroll
        for (int ko = 0; ko < 8; ++ko) {
            acc0 = __builtin_amdgcn_mfma_f32_16x16x32_f16(a0[ko], b[ko], acc0, 0, 0, 0);
            acc1 = __builtin_amdgcn_mfma_f32_16x16x32_f16(a1[ko], b[ko], acc1, 0, 0, 0);
        }
        const int c = g * 16 + ln;
        #pragma unroll
        for (int r = 0; r < 4; ++r) {       // D[m][n]: n=ln, m=qd*4+r; ascending c -> strict >
            if (acc0[r] > bv0[r]) { bv0[r] = acc0[r]; bi0[r] = c; }
            if (acc1[r] > bv1[r]) { bv1[r] = acc1[r]; bi1[r] = c; }
        }
    };

    #pragma unroll 1
    for (int g = 0; g < 32; g += 2) {
        {   // prefetch tile g+1 -> bb
            const _Float16* bn = bswz + (g + 1) * 4096 + lane * 8;
            #pragma unroll
            for (int ko = 0; ko < 8; ++ko) bb[ko] = *(const half8_t*)(bn + ko * 512);
        }
        const float bias_n = bias[(g + 1) * 16 + ln];
        compute(g, ba, bias_c);
        if (g + 2 < 32) {   // prefetch tile g+2 -> ba
            const _Float16* bn = bswz + (g + 2) * 4096 + lane * 8;
            #pragma unroll
            for (int ko = 0; ko < 8; ++ko) ba[ko] = *(const half8_t*)(bn + ko * 512);
            bias_c = bias[(g + 2) * 16 + ln];
        }
        compute(g + 1, bb, bias_n);
    }

    // per-row argmax across the 16 lanes of each quad (different code subsets)
    #pragma unroll
    for (int r = 0; r < 4; ++r) {
        #pragma unroll
        for (int off = 1; off < 16; off <<= 1) {
            const float ov0 = __shfl_xor(bv0[r], off);
            const int   oi0 = __shfl_xor(bi0[r], off);
            if (ov0 > bv0[r] || (ov0 == bv0[r] && oi0 < bi0[r])) { bv0[r] = ov0; bi0[r] = oi0; }
            const float ov1 = __shfl_xor(bv1[r], off);
            const int   oi1 = __shfl_xor(bi1[r], off);
            if (ov1 > bv1[r] || (ov1 == bv1[r] && oi1 < bi1[r])) { bv1[r] = ov1; bi1[r] = oi1; }
        }
    }

    // broadcast row ssq to all lanes (ssq for row m lives in lanes with ln==m&15)
    float ssA[4], ssB[4];
    #pragma unroll
    for (int r = 0; r < 4; ++r) {
        ssA[r] = __shfl(ssq0, qd * 4 + r);
        ssB[r] = __shfl(ssq1, qd * 4 + r);
    }

    // leaders (ln==0): winners -> lidx/lhist, loss via identity (no x re-read)
    float lsum = 0.0f;
    if (ln == 0) {
        #pragma unroll
        for (int r = 0; r < 4; ++r) {
            const int row = qd * 4 + r;
            const float2 c0 = cab[bi0[r]];
            lidx[wave * 32 + row] = bi0[r];
            atomicAdd(&lhist[bi0[r]], 1u);
            lsum += ssA[r] + c0.x + c0.y * bv0[r];
            const float2 c1 = cab[bi1[r]];
            lidx[wave * 32 + 16 + row] = bi1[r];
            atomicAdd(&lhist[bi1[r]], 1u);
            lsum += ssB[r] + c1.x + c1.y * bv1[r];
        }
        lred[wave * 4 + qd] = lsum;
    }

    // epilogue: per wave, write 32 rows of gathered raw codebook (output == q exactly);
    // lidx written by this wave's leaders -> in-wave LDS ordering, no barrier needed.
    {
        float* og = out + (size_t)r0 * kD;
        #pragma unroll 4
        for (int i = 0; i < 32; ++i) {
            const int idx = lidx[wave * 32 + i];
            const float4 q = *(const float4*)(emb + (size_t)idx * kD + lane * 4);
            *(float4*)(og + i * kD + lane * 4) = q;
        }
    }

    __syncthreads();
    if (t == 0) {
        float bs = 0.f;
        #pragma unroll
        for (int w = 0; w < 16; ++w) bs += lred[w];
        atomicAdd(loss_accum, bs);
    }
    // flush histogram (skip zero bins)
    const unsigned int h0 = lhist[t];
    if (h0) atomicAdd(&hist[t], h0);
    const unsigned int h1 = lhist[t + 256];
    if (h1) atomicAdd(&hist[t + 256], h1);
}

// ---------------- final: scalars ----------------
__global__ void vq_final(const unsigned int* __restrict__ hist,
                         const float* __restrict__ loss_accum,
                         float* __restrict__ out) {
    const int t = threadIdx.x;  // 256 threads
    __shared__ float sr[4];
    float s = 0.0f;
    for (int b = t; b < kM; b += 256) {
        const float p = (float)hist[b] * (1.0f / 65536.0f);
        s += p * logf(p + 1e-10f);
    }
    #pragma unroll
    for (int off = 32; off > 0; off >>= 1) s += __shfl_xor(s, off);
    if ((t & 63) == 0) sr[t >> 6] = s;
    __syncthreads();
    if (t == 0) {
        const float tot = sr[0] + sr[1] + sr[2] + sr[3];
        out[16777217] = expf(-tot);                           // perplexity
        out[16777216] = loss_accum[0] * (1.0f / 16777216.0f); // commitment loss
    }
}

extern "C" void kernel_launch(void* const* d_in, const int* in_sizes, int n_in,
                              void* d_out, int out_size, void* d_ws, size_t ws_size,
                              hipStream_t stream) {
    const float* x = (const float*)d_in[0];     // (16,4096,256) fp32
    const float* emb = (const float*)d_in[1];   // (512,256) fp32
    char* ws = (char*)d_ws;
    _Float16* bswz = (_Float16*)ws;                           // 512*256*2 = 262144 B
    float* bias = (float*)(ws + 262144);                      // 2048 B
    unsigned int* hist = (unsigned int*)(ws + 262144 + 2048); // 2048 B
    float* loss = (float*)(ws + 262144 + 4096);               // 16 B (padded)
    float2* cab = (float2*)(ws + 262144 + 4096 + 16);         // 4096 B
    float* out = (float*)d_out;

    vq_prep<<<kM, 64, 0, stream>>>(emb, bswz, bias, cab, hist, loss);
    vq_main<<<kRows / kBM, 256, 0, stream>>>(x, emb, bswz, bias, cab, hist, loss, out);
    vq_final<<<1, 256, 0, stream>>>(hist, loss, out);
}